// Round 10
// baseline (205.716 us; speedup 1.0000x reference)
//
#include <hip/hip_runtime.h>
#include <hip/hip_bf16.h>

#define C 64   // C_IN == C_OUT == 64
#define NCOPY 8
#define FXSCALE 16777216.0f            // 2^24
#define LOW44 ((1ULL << 44) - 1)

typedef unsigned short u16;

__device__ __forceinline__ u16 f2bf_rne(float v) {
    unsigned u = __float_as_uint(v);
    u += 0x7FFFu + ((u >> 16) & 1u);
    return (u16)(u >> 16);
}
__device__ __forceinline__ float bf2f(u16 u) {
    return __uint_as_float((unsigned)u << 16);
}

// --- Kernel 1: fused histogram (x4 unrolled). One u64 atomic per edge:
// bits [44:63] = count, [0:43] = fixed-point sum(ew). Return -> rank.
__global__ __launch_bounds__(256) void hist8_kernel(const int* __restrict__ row,
                                                    const float* __restrict__ ew,
                                                    unsigned long long* __restrict__ cd8,
                                                    u16* __restrict__ rank16,
                                                    int E, int N) {
    int t = threadIdx.x;
    int base = blockIdx.x * 1024;
    int copy = blockIdx.x & (NCOPY - 1);
    size_t cb = (size_t)copy * N;

    unsigned long long old[4];
    int e[4];
#pragma unroll
    for (int u = 0; u < 4; u++) {
        e[u] = base + u * 256 + t;
        if (e[u] < E) {
            int r = row[e[u]];
            unsigned long long fx = (unsigned long long)__float2uint_rn(ew[e[u]] * FXSCALE);
            unsigned long long inc = (1ULL << 44) | fx;
            old[u] = atomicAdd(&cd8[cb + r], inc);
        }
    }
#pragma unroll
    for (int u = 0; u < 4; u++) {
        if (e[u] < E) rank16[e[u]] = (u16)(old[u] >> 44);
    }
}

// --- Scan phase A: reduce 8 copies -> cnt, dis; per-block sums of cnt ---
__global__ __launch_bounds__(256) void scanA_kernel(const unsigned long long* __restrict__ cd8,
                                                    int* __restrict__ cnt,
                                                    float* __restrict__ dis,
                                                    int* __restrict__ bsum, int N) {
    __shared__ int s[256];
    int t = threadIdx.x;
    int i = blockIdx.x * 256 + t;
    int cv = 0;
    unsigned long long dfx = 0;
    if (i < N) {
#pragma unroll
        for (int c = 0; c < NCOPY; c++) {
            unsigned long long v = cd8[(size_t)c * N + i];
            cv += (int)(v >> 44);
            dfx += (v & LOW44);
        }
        cnt[i] = cv;
        float dv = (float)dfx * (1.0f / FXSCALE);
        dis[i] = (dv > 0.0f) ? rsqrtf(dv) : 0.0f;
    }
    s[t] = cv;
    __syncthreads();
    for (int off = 128; off > 0; off >>= 1) {
        if (t < off) s[t] += s[t + off];
        __syncthreads();
    }
    if (t == 0) bsum[blockIdx.x] = s[0];
}

// --- Scan phase B: exclusive scan of G (<=256) block sums; writes rowptr[N] ---
__global__ __launch_bounds__(256) void scanB_kernel(int* __restrict__ bsum,
                                                    int* __restrict__ rowptr,
                                                    int G, int N) {
    __shared__ int s[256];
    int t = threadIdx.x;
    int v = (t < G) ? bsum[t] : 0;
    s[t] = v;
    __syncthreads();
    for (int off = 1; off < 256; off <<= 1) {
        int u = (t >= off) ? s[t - off] : 0;
        __syncthreads();
        s[t] += u;
        __syncthreads();
    }
    if (t < G) bsum[t] = s[t] - v;          // exclusive block prefix
    if (t == 255) rowptr[N] = s[255];       // total edge count
}

// --- Scan phase C: rowptr + per-copy start slots + xg = bf16(dis .* x) ---
__global__ __launch_bounds__(256) void scanC_kernel(const int* __restrict__ cnt,
                                                    const unsigned long long* __restrict__ cd8,
                                                    int* __restrict__ start8,
                                                    const int* __restrict__ bsum,
                                                    int* __restrict__ rowptr,
                                                    const float* __restrict__ dis,
                                                    const float* __restrict__ x,
                                                    u16* __restrict__ xg,
                                                    int N) {
    __shared__ int s[256];
    __shared__ float sdis[256];
    int t = threadIdx.x;
    int i = blockIdx.x * 256 + t;
    int v = (i < N) ? cnt[i] : 0;
    if (i < N) sdis[t] = dis[i];
    s[t] = v;
    __syncthreads();
    for (int off = 1; off < 256; off <<= 1) {
        int u = (t >= off) ? s[t - off] : 0;
        __syncthreads();
        s[t] += u;
        __syncthreads();
    }
    if (i < N) {
        int rp = bsum[blockIdx.x] + s[t] - v;  // exclusive prefix
        rowptr[i] = rp;
        int run = rp;
#pragma unroll
        for (int c = 0; c < NCOPY; c++) {
            int tmp = (int)(cd8[(size_t)c * N + i] >> 44);
            start8[(size_t)c * N + i] = run;   // start slot for this copy
            run += tmp;
        }
    }
    // phase 2: xg = bf16(dis .* x) for this block's 256 rows (coalesced)
    size_t nb = (size_t)blockIdx.x * 16384;    // element base (256 rows x 64 ch)
#pragma unroll 1
    for (int it = 0; it < 16; it++) {
        int idx4 = it * 256 + t;               // float4 index 0..4095
        int lr = idx4 >> 4;                    // local row
        int gr = blockIdx.x * 256 + lr;
        if (gr < N) {
            float4 vv = *(const float4*)(x + nb + (size_t)idx4 * 4);
            float di = sdis[lr];
            ushort4 o;
            o.x = f2bf_rne(vv.x * di); o.y = f2bf_rne(vv.y * di);
            o.z = f2bf_rne(vv.z * di); o.w = f2bf_rne(vv.w * di);
            *(ushort4*)(xg + nb + (size_t)idx4 * 4) = o;
        }
    }
}

// --- Kernel 4: atomic-free scatter: pos = start8[copy][r] + rank16[e].
// Stores packed edge: (col << 16) | bf16(ew). Normalization factored out.
__global__ __launch_bounds__(256) void scatter_kernel(const int* __restrict__ row,
                                                      const int* __restrict__ col,
                                                      const float* __restrict__ ew,
                                                      const int* __restrict__ start8,
                                                      const u16* __restrict__ rank16,
                                                      unsigned* __restrict__ epk,
                                                      int E, int N) {
    int t = threadIdx.x;
    int base = blockIdx.x * 1024;
    int copy = blockIdx.x & (NCOPY - 1);
    size_t cb = (size_t)copy * N;
#pragma unroll
    for (int u = 0; u < 4; u++) {
        int e = base + u * 256 + t;
        if (e < E) {
            int r = row[e];
            unsigned pk = ((unsigned)col[e] << 16) | (unsigned)f2bf_rne(ew[e]);
            int pos = start8[cb + r] + (int)rank16[e];
            epk[pos] = pk;
        }
    }
}

// --- Kernel 5: CSR SpMM, 2 edges/wave (half-wave each), packed u32 edges,
// bf16x2 gathers of the dis-prescaled operand. Output: out32 = -dis_r * S,
// outbf = bf16(dis_r * out32) for the next propagation.
__global__ __launch_bounds__(256) void spmm_csr_kernel(
        const int* __restrict__ rowptr,
        const unsigned* __restrict__ epk,   // (col<<16)|bf16(ew)
        const float* __restrict__ dis,
        const unsigned* __restrict__ h32,   // bf16x2 [N][32], pre-scaled by dis
        float* __restrict__ out32,          // fp32 [N][C]
        unsigned* __restrict__ outbf,       // bf16x2 [N][32]
        int N, int writebf) {
    int wid = (blockIdx.x * blockDim.x + threadIdx.x) >> 6;  // row id
    int lane = threadIdx.x & 63;
    if (wid >= N) return;
    int half = lane >> 5;        // which edge of the pair
    int cp   = lane & 31;        // channel pair 0..31
    int beg = rowptr[wid];
    int end = rowptr[wid + 1];
    float ax0 = 0.f, ay0 = 0.f, ax1 = 0.f, ay1 = 0.f;
    float ax2 = 0.f, ay2 = 0.f, ax3 = 0.f, ay3 = 0.f;
    for (int base = beg; base < end; base += 64) {
        int idx = base + lane;
        // pad = 0 -> col 0, w = 0: harmless gather of row 0
        unsigned ed = (idx < end) ? epk[idx] : 0u;
        int cnt = end - base; if (cnt > 64) cnt = 64;
        for (int j = 0; j < cnt; j += 8) {
            unsigned e0 = (unsigned)__shfl((int)ed, j + half);
            unsigned e1 = (unsigned)__shfl((int)ed, j + 2 + half);
            unsigned e2 = (unsigned)__shfl((int)ed, j + 4 + half);
            unsigned e3 = (unsigned)__shfl((int)ed, j + 6 + half);
            float w0 = bf2f((u16)(e0 & 0xffffu)); int c0 = (int)(e0 >> 16);
            float w1 = bf2f((u16)(e1 & 0xffffu)); int c1 = (int)(e1 >> 16);
            float w2 = bf2f((u16)(e2 & 0xffffu)); int c2 = (int)(e2 >> 16);
            float w3 = bf2f((u16)(e3 & 0xffffu)); int c3 = (int)(e3 >> 16);
            unsigned hv0 = h32[(size_t)c0 * 32 + cp];
            unsigned hv1 = h32[(size_t)c1 * 32 + cp];
            unsigned hv2 = h32[(size_t)c2 * 32 + cp];
            unsigned hv3 = h32[(size_t)c3 * 32 + cp];
            ax0 = fmaf(w0, bf2f((u16)(hv0 & 0xffffu)), ax0);
            ay0 = fmaf(w0, bf2f((u16)(hv0 >> 16)),     ay0);
            ax1 = fmaf(w1, bf2f((u16)(hv1 & 0xffffu)), ax1);
            ay1 = fmaf(w1, bf2f((u16)(hv1 >> 16)),     ay1);
            ax2 = fmaf(w2, bf2f((u16)(hv2 & 0xffffu)), ax2);
            ay2 = fmaf(w2, bf2f((u16)(hv2 >> 16)),     ay2);
            ax3 = fmaf(w3, bf2f((u16)(hv3 & 0xffffu)), ax3);
            ay3 = fmaf(w3, bf2f((u16)(hv3 >> 16)),     ay3);
        }
    }
    float ax = (ax0 + ax1) + (ax2 + ax3);
    float ay = (ay0 + ay1) + (ay2 + ay3);
    // combine half-waves
    float bx = __shfl(ax, cp + 32);
    float by = __shfl(ay, cp + 32);
    if (half == 0) {
        float dr = dis[wid];
        float rx = -dr * (ax + bx);
        float ry = -dr * (ay + by);
        *(float2*)(out32 + (size_t)wid * C + 2 * cp) = make_float2(rx, ry);
        if (writebf) {
            unsigned pk = (unsigned)f2bf_rne(dr * rx) | ((unsigned)f2bf_rne(dr * ry) << 16);
            outbf[(size_t)wid * 32 + cp] = pk;
        }
    }
}

// --- Kernel 6: fused dense epilogue as register-tiled GEMM ---
// out = relu([x | T1 | 2P-x] @ Wcat + b), Wcat = [192][64] (W row-major)
__global__ __launch_bounds__(256) void final_gemm_kernel(
        const float* __restrict__ x,
        const float* __restrict__ T1,
        const float* __restrict__ P,
        const float* __restrict__ W,   // [192][64] row-major
        const float* __restrict__ b,
        float* __restrict__ out, int N) {
    __shared__ float As[16][64];  // [k][node]
    __shared__ float Ws[16][64];  // [k][col]

    int t  = threadIdx.x;
    int tx = t & 15;
    int ty = t >> 4;
    int n0 = blockIdx.x * 64;

    int sn = t >> 2;
    int skb = (t & 3) * 4;

    float acc[4][4];
#pragma unroll
    for (int i = 0; i < 4; i++)
#pragma unroll
        for (int j = 0; j < 4; j++) acc[i][j] = 0.0f;

#pragma unroll 1
    for (int s = 0; s < 12; s++) {
        float4 wv = *(const float4*)(W + s * 1024 + t * 4);
        int nn = n0 + sn;
        float4 av = make_float4(0.f, 0.f, 0.f, 0.f);
        if (nn < N) {
            if (s < 4) {
                av = *(const float4*)(x + (size_t)nn * C + s * 16 + skb);
            } else if (s < 8) {
                av = *(const float4*)(T1 + (size_t)nn * C + (s - 4) * 16 + skb);
            } else {
                float4 pv = *(const float4*)(P + (size_t)nn * C + (s - 8) * 16 + skb);
                float4 xv = *(const float4*)(x + (size_t)nn * C + (s - 8) * 16 + skb);
                av = make_float4(2.0f * pv.x - xv.x, 2.0f * pv.y - xv.y,
                                 2.0f * pv.z - xv.z, 2.0f * pv.w - xv.w);
            }
        }
        __syncthreads();
        {
            int wk = (t * 4) >> 6;
            int wc = (t * 4) & 63;
            *(float4*)&Ws[wk][wc] = wv;
        }
        As[skb + 0][sn] = av.x;
        As[skb + 1][sn] = av.y;
        As[skb + 2][sn] = av.z;
        As[skb + 3][sn] = av.w;
        __syncthreads();

#pragma unroll
        for (int kk = 0; kk < 16; kk++) {
            float4 a4 = *(const float4*)&As[kk][ty * 4];
            float4 w4 = *(const float4*)&Ws[kk][tx * 4];
            float ar[4] = {a4.x, a4.y, a4.z, a4.w};
            float wr[4] = {w4.x, w4.y, w4.z, w4.w};
#pragma unroll
            for (int i = 0; i < 4; i++)
#pragma unroll
                for (int j = 0; j < 4; j++)
                    acc[i][j] = fmaf(ar[i], wr[j], acc[i][j]);
        }
    }

    float4 bv = *(const float4*)(b + tx * 4);
    float br[4] = {bv.x, bv.y, bv.z, bv.w};
#pragma unroll
    for (int i = 0; i < 4; i++) {
        int node = n0 + ty * 4 + i;
        if (node < N) {
            float4 o;
            o.x = fmaxf(acc[i][0] + br[0], 0.0f);
            o.y = fmaxf(acc[i][1] + br[1], 0.0f);
            o.z = fmaxf(acc[i][2] + br[2], 0.0f);
            o.w = fmaxf(acc[i][3] + br[3], 0.0f);
            *(float4*)(out + (size_t)node * C + tx * 4) = o;
        }
    }
}

extern "C" void kernel_launch(void* const* d_in, const int* in_sizes, int n_in,
                              void* d_out, int out_size, void* d_ws, size_t ws_size,
                              hipStream_t stream) {
    const float* x  = (const float*)d_in[0];
    const int*   ei = (const int*)d_in[1];
    const float* ew = (const float*)d_in[2];
    const float* W  = (const float*)d_in[3];
    const float* b  = (const float*)d_in[4];
    float* out = (float*)d_out;

    const int N = in_sizes[0] / C;
    const int E = in_sizes[2];
    const int* row = ei;        // edge_index[0]
    const int* col = ei + E;    // edge_index[1]

    char* ws = (char*)d_ws;
    size_t off = 0;
    auto alloc = [&](size_t bytes) {
        void* p = ws + off;
        off = (off + bytes + 255) & ~(size_t)255;
        return p;
    };
    float*    dis    = (float*)alloc((size_t)N * 4);
    int*      cnt    = (int*)alloc((size_t)N * 4);
    int*      rowptr = (int*)alloc((size_t)(N + 1) * 4);
    unsigned* epk    = (unsigned*)alloc((size_t)E * 4);     // packed CSR edges
    float*    T1     = (float*)alloc((size_t)N * C * 4);
    float*    P      = (float*)alloc((size_t)N * C * 4);
    int*      bsum   = (int*)alloc((size_t)256 * 4);
    unsigned long long* cd8 = (unsigned long long*)alloc((size_t)NCOPY * N * 8);
    int*      start8 = (int*)alloc((size_t)NCOPY * N * 4);
    u16*      rank16 = (u16*)alloc((size_t)E * 2);
    u16*      xg     = (u16*)alloc((size_t)N * C * 2);      // bf16 dis.*x
    u16*      T1g    = (u16*)alloc((size_t)N * C * 2);      // bf16 dis.*T1

    hipMemsetAsync(cd8, 0, (size_t)NCOPY * N * 8, stream);

    const int B = 256;
    const int G = (N + B - 1) / B;  // 196 <= 256

    int histBlocks = (E + 1023) / 1024;
    hist8_kernel<<<histBlocks, B, 0, stream>>>(row, ew, cd8, rank16, E, N);
    scanA_kernel<<<G, B, 0, stream>>>(cd8, cnt, dis, bsum, N);
    scanB_kernel<<<1, B, 0, stream>>>(bsum, rowptr, G, N);
    scanC_kernel<<<G, B, 0, stream>>>(cnt, cd8, start8, bsum, rowptr,
                                      dis, x, xg, N);
    scatter_kernel<<<histBlocks, B, 0, stream>>>(row, col, ew, start8,
                                                 rank16, epk, E, N);

    int spmm_blocks = (int)(((long long)N * 64 + B - 1) / B);
    spmm_csr_kernel<<<spmm_blocks, B, 0, stream>>>(rowptr, epk, dis,
                                                   (const unsigned*)xg,
                                                   T1, (unsigned*)T1g, N, 1);
    spmm_csr_kernel<<<spmm_blocks, B, 0, stream>>>(rowptr, epk, dis,
                                                   (const unsigned*)T1g,
                                                   P, (unsigned*)T1g, N, 0);

    final_gemm_kernel<<<(N + 63) / 64, B, 0, stream>>>(x, T1, P, W, b, out, N);
}